// Round 9
// baseline (214.110 us; speedup 1.0000x reference)
//
#include <hip/hip_runtime.h>
#include <hip/hip_bf16.h>

// Problem constants (fixed by the reference).
constexpr int T  = 4096;   // contraction dim (K = t)
constexpr int Bb = 8;      // batch
constexpr int C  = 512;    // channels (N)
constexpr int S  = 2048;   // groups (M)
constexpr int BC = Bb * C; // 4096 floats: t-row stride of x, s-row stride of out

constexpr int BK = 32;        // K-tile staged per iteration
constexpr int NK = T / BK;    // 128 iterations

typedef __bf16 bf16x8 __attribute__((ext_vector_type(8)));
typedef float  f32x16 __attribute__((ext_vector_type(16)));
typedef float  f32x4  __attribute__((ext_vector_type(4)));

// pack two f32 -> one dword of 2x bf16 (lo = first, hi = second), RNE.
__device__ inline unsigned pk2(float lo, float hi) {
    union { __hip_bfloat16 h; unsigned short u; } a, b;
    a.h = __float2bfloat16(lo);
    b.h = __float2bfloat16(hi);
    return ((unsigned)b.u << 16) | (unsigned)a.u;
}

// 16B-slot swizzle: o = s ^ ((s>>2)&7). Bijective for any width (bits >=3
// of o equal s; bit2(s) = bit2(o)^bit4(o) recovers the mask). Spreads the
// strided staging writes across bank groups; fragment reads stay a
// lane-permuted contiguous 512B region (conflict-free b128).
__device__ inline int slot16(int s) { return s ^ ((s >> 2) & 7); }

// out[0,b,c] = leftmost[c]
__global__ void left_fill(const float* __restrict__ left, float* __restrict__ out) {
    int i = blockIdx.x * blockDim.x + threadIdx.x;   // 0..BC-1
    if (i < BC) out[i] = left[i & (C - 1)];
}

// Per-b GEMM: out[(s+1),b,c] = sum_t mask[b,t,s] * x[t,b,c].
// ROUND-9: tile 256(s) x 128(c)  [L2 tile-reread traffic 2.1GB -> 1.5GB]
// + DEPTH-2 register prefetch over 3 LDS buffers [2 iters + 2 barriers of
// load-latency cover vs 1 in r8].
// Block 512 thr = 8 waves (4m x 2n), wave tile 64x64, BK=32.
// Grid 256 = 1 block/CU (whole grid resident). launch_bounds(512,2) ->
// 256-VGPR cap: acc 64 + two 32-reg staging sets fit WITHOUT r7's spill.
// XCD swizzle: 256 blocks = 8 XCDs x 32 slots; XCD i owns batch b=i's whole
// (mt,nt) plane -> all 4 nt-sharers of each mask panel and all 8 mt-sharers
// of each x panel are co-resident on one XCD; per-K-iter XCD working set
// ~320KB << 4MB L2.
// LDS per buffer: A = oct*4096B + slot16(scol)*16B + (t&7)*2B   (16KB)
//                 B at +16384 = oct*2048B + slot16(ccol)*16B + (t&7)*2B (8KB)
// buffer stride 24576B, 3 buffers = 72KB. One ds_read_b128 per fragment.
__global__ __launch_bounds__(512, 2) void ds_gemm(
    const float* __restrict__ x,
    const float* __restrict__ mask,
    float* __restrict__ out)
{
    __shared__ __align__(16) unsigned char smem[73728];  // 3 x (16KB A | 8KB B)

    // ---- chunked XCD swizzle (bijective: 256 = 8 xcd * 32 slots) ----
    const int bid0 = blockIdx.x;
    const int xcd  = bid0 & 7;            // HW XCD (round-robin dispatch)
    const int slot = bid0 >> 3;           // 0..31 within this XCD
    const int b    = xcd;                 // batch plane owned by this XCD
    const int mt   = slot & 7;            // s-tile (0..7), 256 rows each
    const int nt   = slot >> 3;           // c-tile (0..3), 128 cols each

    const int tid  = threadIdx.x;
    const int lane = tid & 63;
    const int wave = tid >> 6;       // 0..7
    const int wm = wave >> 1;        // s-quarter (0..3)
    const int wn = wave & 1;         // c-half    (0..1)
    const int lm = lane & 31;
    const int kg = lane >> 5;

    // ---------------- staging roles (wave-uniform branches)
    // waves 0-3 (tid 0-255):  A = mask tile 256s x 32t  (8192 f32; 32/thread)
    // waves 4-5 (tid 256-383): B = x tile 128c x 32t    (4096 f32; 32/thread)
    // waves 6-7: compute-only.
    const bool stA = (tid < 256);
    const bool stB = (tid >= 256 && tid < 384);
    const int  ii  = stA ? tid : (tid - 256);
    const int  sg  = stA ? (ii & 63) : (ii & 31);   // 4-wide col group
    const int  tg  = stA ? (ii >> 6) : (ii >> 5);   // t-oct 0..3

    const float* gsrc = stA
        ? mask + (size_t)b * T * S + (size_t)(tg * 8) * S + mt * 256 + sg * 4
        : x    + (size_t)(tg * 8) * BC + b * C + nt * 128 + sg * 4;
    const size_t grow  = stA ? (size_t)S : (size_t)BC;  // floats per t-row
    const size_t gstep = grow * BK;                      // advance per K-tile

    int waddr[4];
#pragma unroll
    for (int j = 0; j < 4; ++j)
        waddr[j] = stA ? (tg * 4096 + slot16(sg * 4 + j) * 16)
                       : (16384 + tg * 2048 + slot16(sg * 4 + j) * 16);

    // ---------------- fragment read addresses (oct = kk*2 + kg)
    int raddrA[2][2], raddrB[2][2];
#pragma unroll
    for (int kk = 0; kk < 2; ++kk)
#pragma unroll
        for (int q = 0; q < 2; ++q) {
            raddrA[kk][q] = (kk * 2 + kg) * 4096 + slot16(wm * 64 + q * 32 + lm) * 16;
            raddrB[kk][q] = 16384 + (kk * 2 + kg) * 2048 + slot16(wn * 64 + q * 32 + lm) * 16;
        }

    f32x16 acc[2][2] = {};
    f32x4  L0[8], L1[8];   // depth-2 staging register sets

#define LOAD_TILE(Lr, k)                                                    \
    if (stA || stB) {                                                       \
        const float* p_ = gsrc + (size_t)(k) * gstep;                       \
        _Pragma("unroll") for (int r = 0; r < 8; ++r)                       \
            Lr[r] = *(const f32x4*)(p_ + (size_t)r * grow);                 \
    }

#define WRITE_TILE(Lr, buf)                                                 \
    if (stA || stB) {                                                       \
        const int boff_ = (buf) * 24576;                                    \
        _Pragma("unroll") for (int j = 0; j < 4; ++j) {                     \
            uint4 w_;                                                       \
            w_.x = pk2(Lr[0][j], Lr[1][j]);                                 \
            w_.y = pk2(Lr[2][j], Lr[3][j]);                                 \
            w_.z = pk2(Lr[4][j], Lr[5][j]);                                 \
            w_.w = pk2(Lr[6][j], Lr[7][j]);                                 \
            *(uint4*)(smem + boff_ + waddr[j]) = w_;                        \
        }                                                                   \
    }

#define COMPUTE(buf)                                                        \
    {                                                                       \
        const int boff_ = (buf) * 24576;                                    \
        _Pragma("unroll") for (int kk = 0; kk < 2; ++kk) {                  \
            bf16x8 a0_ = *(const bf16x8*)(smem + boff_ + raddrA[kk][0]);    \
            bf16x8 a1_ = *(const bf16x8*)(smem + boff_ + raddrA[kk][1]);    \
            bf16x8 b0_ = *(const bf16x8*)(smem + boff_ + raddrB[kk][0]);    \
            bf16x8 b1_ = *(const bf16x8*)(smem + boff_ + raddrB[kk][1]);    \
            acc[0][0] = __builtin_amdgcn_mfma_f32_32x32x16_bf16(a0_, b0_, acc[0][0], 0, 0, 0); \
            acc[0][1] = __builtin_amdgcn_mfma_f32_32x32x16_bf16(a0_, b1_, acc[0][1], 0, 0, 0); \
            acc[1][0] = __builtin_amdgcn_mfma_f32_32x32x16_bf16(a1_, b0_, acc[1][0], 0, 0, 0); \
            acc[1][1] = __builtin_amdgcn_mfma_f32_32x32x16_bf16(a1_, b1_, acc[1][1], 0, 0, 0); \
        }                                                                   \
    }

    // Prologue: two tiles in flight (depth-2).
    LOAD_TILE(L0, 0);
    LOAD_TILE(L1, 1);

    // iter k: WRITE tile k (loaded 2 iters ago -> cover = 2 COMPUTEs + 2
    // barriers); re-issue that register set for tile k+2; barrier; COMPUTE.
    // Buffer k%3 was last read at COMPUTE(k-3); barriers at k-2,k-1 separate
    // that read from this write -> 3 buffers + 1 barrier/iter is safe.
    for (int k = 0; k < NK; ++k) {
        const int buf = k % 3;
        if (k & 1) {
            WRITE_TILE(L1, buf);
            if (k + 2 < NK) LOAD_TILE(L1, k + 2);
        } else {
            WRITE_TILE(L0, buf);
            if (k + 2 < NK) LOAD_TILE(L0, k + 2);
        }
        __syncthreads();
        COMPUTE(buf);
    }

#undef LOAD_TILE
#undef WRITE_TILE
#undef COMPUTE

    // Epilogue. C/D layout (HW-verified): col = lane&31, row = (r&3)+8*(r>>2)+4*(lane>>5).
    const int s_w = mt * 256 + wm * 64;
    const int c_w = nt * 128 + wn * 64;
    float* outp = out + BC;   // skip leftmost row
#pragma unroll
    for (int m2 = 0; m2 < 2; ++m2)
#pragma unroll
        for (int n2 = 0; n2 < 2; ++n2)
#pragma unroll
            for (int r = 0; r < 16; ++r) {
                const int row  = (r & 3) + 8 * (r >> 2) + 4 * kg;
                const int srow = s_w + m2 * 32 + row;
                const int ccol = c_w + n2 * 32 + lm;
                outp[(size_t)srow * BC + b * C + ccol] = acc[m2][n2][r];
            }
}

extern "C" void kernel_launch(void* const* d_in, const int* in_sizes, int n_in,
                              void* d_out, int out_size, void* d_ws, size_t ws_size,
                              hipStream_t stream) {
    const float* x    = (const float*)d_in[0];  // [T,B,C] fp32
    const float* mask = (const float*)d_in[1];  // [B,T,S] fp32
    // d_in[2] = size_of_groups (int64) — unused by the 'average' reference path
    const float* left = (const float*)d_in[3];  // [1,1,C] fp32
    float* out = (float*)d_out;                 // [S+1,B,C] fp32

    left_fill<<<BC / 256, 256, 0, stream>>>(left, out);
    ds_gemm<<<Bb * (S / 256) * (C / 128), 512, 0, stream>>>(x, mask, out);
}